// Round 6
// baseline (130.064 us; speedup 1.0000x reference)
//
#include <hip/hip_runtime.h>
#include <hip/hip_bf16.h>

typedef __attribute__((ext_vector_type(4))) float f32x4;
typedef __attribute__((ext_vector_type(2))) long long l64x2;

constexpr int kB = 4, kC = 64, kH = 64, kW = 64;
constexpr int kHW = kH * kW;      // 4096
constexpr int kD  = kC * 9;       // 576
constexpr int KSPLIT = 8;
constexpr int KBLK = 32;
constexpr int QWAVE = 64;         // q rows per wave (4 groups of 16)
constexpr int QWG = 128;          // 2 waves * 64 q
constexpr int NTILE = kHW / KSPLIT / KBLK;   // 16
constexpr int ROWB8 = 640;        // padded fp8 row bytes (40 chunks of 16B; 36 data + 4 holes)
constexpr int TILEB = KBLK * ROWB8;          // 20480 B per K-tile

// Features pre-scaled by sqrt(10*log2e): S = corr in exp2-logit space.
#define FSCALE 3.79828370f
#define FS2    14.4269504089f     // FSCALE^2 = 10*log2(e)
#define SEED_SLACK 64.0f          // fp32-seed vs fp8-diag tolerance

// ---------------- Phase 0: per-pixel sum of squared channels (for self-logit seed) ----------------
__global__ __launch_bounds__(256)
void nlwa_selfsq(const float* __restrict__ feat, float* __restrict__ sq) {
    int idx = blockIdx.x * 256 + threadIdx.x;   // b*4096 + p
    if (idx >= kB * kHW) return;
    int b = idx >> 12, p = idx & 4095;
    const float* f = feat + (size_t)b * kC * kHW + p;
    float s = 0.f;
    #pragma unroll 8
    for (int c = 0; c < kC; ++c) { float v = f[c * kHW]; s = fmaf(v, v, s); }
    sq[idx] = s;
}

// ---------------- Phase 1: unfold + fp8(e4m3) + pre-scale + XOR pre-swizzle ----------------
// d decomposed: window w=d>>5, kgroup kg=(d>>3)&3, elem e=d&7, pair p=w>>1, half w01=w&1.
// logical 16B-chunk c = p*4+kg (0..35); physical chunk = c ^ (v&7) within 40-chunk padded row.
__global__ __launch_bounds__(256)
void nlwa_unfold(const float* __restrict__ feat, unsigned char* __restrict__ Kd) {
    int idx = blockIdx.x * 256 + threadIdx.x;
    if (idx >= kB * kHW * kD) return;
    int d = idx % kD;
    int v = (idx / kD) % kHW;
    int b = idx / (kD * kHW);
    int c = d / 9, dl = d % 9;
    int y = (v >> 6) + dl / 3 - 1;
    int x = (v & 63) + dl % 3 - 1;
    float val = 0.f;
    if ((unsigned)y < 64u && (unsigned)x < 64u)
        val = feat[((b * kC + c) * kH + y) * kW + x] * FSCALE;
    // e4m3 encode via exponent-shift trick (consistent rounding; |val| < 448, no NaN/Inf)
    unsigned int fb = __builtin_bit_cast(unsigned int, val * 0x1p-120f);
    unsigned int mag = ((fb & 0x7fffffffu) + 0x80000u) >> 20;
    if (mag > 0x7eu) mag = 0x7eu;
    unsigned char u8 = (unsigned char)(((fb >> 31) << 7) | mag);
    int w = d >> 5, kg = (d >> 3) & 3, e = d & 7;
    int cp = ((w >> 1) * 4 + kg) ^ (v & 7);
    Kd[(size_t)(b * kHW + v) * ROWB8 + cp * 16 + (w & 1) * 8 + e] = u8;
}

// ---------------- Phase 2: flash attention, swapped mfma(K,Q) in fp8, 64 q/wave ----------------
__global__ __launch_bounds__(128, 2)
void nlwa_attn(const unsigned char* __restrict__ Kd,
               const float* __restrict__ rgb,
               const float* __restrict__ sq,
               float* __restrict__ part) {
    __shared__ alignas(16) unsigned char Ks[2][KBLK][ROWB8];   // 40,960 B (4 wgs/CU = 160 KiB)

    // XCD-chunked swizzle: 1024 wgs -> 128 consecutive per XCD (4 (b,ks) panels ~1.3MB in its L2)
    int orig = blockIdx.x;
    int wg = (orig & 7) * 128 + (orig >> 3);
    int qblk = wg & 31;
    int pr = wg >> 5;
    int ks = pr & 7;
    int b  = pr >> 3;

    int tid = threadIdx.x, lane = tid & 63, wid = tid >> 6;
    int lr = lane & 15, lg = lane >> 4;       // lg = kgroup
    int x7 = lr & 7;
    int qwave = qblk * QWG + wid * QWAVE;
    int k0 = ks * (kHW / KSPLIT);             // ks*512

    // ---- Q fragments (B-operand): 4 groups x 9 chunk-pairs, int4 = 2 windows each ----
    int4 qb[4][9];
    #pragma unroll
    for (int g = 0; g < 4; ++g) {
        const unsigned char* qbase = Kd + (size_t)(b * kHW + qwave + g * 16 + lr) * ROWB8;
        #pragma unroll
        for (int p = 0; p < 9; ++p)
            qb[g][p] = *(const int4*)(qbase + ((((p * 4 + lg)) ^ x7) << 4));
    }

    // ---- Seed m with fp32 self-logit (3x3 box-sum of per-pixel sum-sq) minus slack ----
    float m[4], l[4] = {0.f, 0.f, 0.f, 0.f};
    float O[4][3] = {{0,0,0},{0,0,0},{0,0,0},{0,0,0}};
    const float* sqb = sq + b * kHW;
    #pragma unroll
    for (int g = 0; g < 4; ++g) {
        int q = qwave + g * 16 + lr, y = q >> 6, x = q & 63;
        float s = 0.f;
        #pragma unroll
        for (int dy = -1; dy <= 1; ++dy)
            #pragma unroll
            for (int dx = -1; dx <= 1; ++dx) {
                int yy = y + dy, xx = x + dx;
                if ((unsigned)yy < 64u && (unsigned)xx < 64u) s += sqb[yy * 64 + xx];
            }
        m[g] = s * FS2 - SEED_SLACK;
    }

    const unsigned char* ksrc = Kd + (size_t)(b * kHW + k0) * ROWB8;
    unsigned char* lds0 = &Ks[0][0][0];

    auto stage = [&](int t, int bufi) {   // flat 20,480-B copy, 10 iters x 128 threads x 16B
        const unsigned char* src = ksrc + (size_t)t * TILEB;
        unsigned char* dstb = lds0 + bufi * TILEB;
        #pragma unroll
        for (int it = 0; it < 10; ++it) {
            int ch = it * 128 + wid * 64;   // wave-uniform base chunk
            __builtin_amdgcn_global_load_lds(
                (const __attribute__((address_space(1))) void*)(src + (size_t)(ch + lane) * 16),
                (__attribute__((address_space(3))) void*)(dstb + (size_t)ch * 16),
                16, 0, 0);
        }
    };

    stage(0, 0);
    __syncthreads();   // tile 0 resident

    // Per-lane LDS read offsets: physical chunk (p*4+lg)^x7 = (p^h)*4 + (lg^lo2)
    int lo2 = x7 & 3, h = x7 >> 2;
    int cb = (lg ^ lo2) << 4;
    int r0 = lr * ROWB8 + cb, r1 = (16 + lr) * ROWB8 + cb;
    int e0 = r0 + h * 64, o0 = r0 - h * 64;   // s=0: even-p / odd-p bases
    int e1 = r1 + h * 64, o1 = r1 - h * 64;   // s=1

    int buf = 0;
    for (int t = 0; t < NTILE; ++t) {
        if (t + 1 < NTILE) stage(t + 1, buf ^ 1);   // prefetch next into other buffer

        const unsigned char* kb = lds0 + buf * TILEB;
        f32x4 acc[4][2];
        #pragma unroll
        for (int g = 0; g < 4; ++g) {
            acc[g][0] = (f32x4){0.f, 0.f, 0.f, 0.f};
            acc[g][1] = (f32x4){0.f, 0.f, 0.f, 0.f};
        }

        #pragma unroll
        for (int p = 0; p < 9; ++p) {
            int4 ka = *(const int4*)(kb + ((p & 1) ? o0 : e0) + p * 64);
            int4 kc = *(const int4*)(kb + ((p & 1) ? o1 : e1) + p * 64);
            l64x2 ka64 = __builtin_bit_cast(l64x2, ka);
            l64x2 kc64 = __builtin_bit_cast(l64x2, kc);
            #pragma unroll
            for (int w01 = 0; w01 < 2; ++w01) {
                long long a0 = ka64[w01], a1 = kc64[w01];
                #pragma unroll
                for (int g = 0; g < 4; ++g) {
                    long long bq = __builtin_bit_cast(l64x2, qb[g][p])[w01];
                    acc[g][0] = __builtin_amdgcn_mfma_f32_16x16x32_fp8_fp8(a0, bq, acc[g][0], 0, 0, 0);
                    acc[g][1] = __builtin_amdgcn_mfma_f32_16x16x32_fp8_fp8(a1, bq, acc[g][1], 0, 0, 0);
                }
            }
        }
        // acc[g][s][r] = S[k = k0 + t*32 + s*16 + lg*4 + r][q = qwave + g*16 + lr]

        float pm[4];
        #pragma unroll
        for (int g = 0; g < 4; ++g)
            pm[g] = fmaxf(
                fmaxf(fmaxf(acc[g][0][0], acc[g][0][1]), fmaxf(acc[g][0][2], acc[g][0][3])),
                fmaxf(fmaxf(acc[g][1][0], acc[g][1][1]), fmaxf(acc[g][1][2], acc[g][1][3])));

        float dmx = fmaxf(fmaxf(pm[0] - m[0], pm[1] - m[1]),
                          fmaxf(pm[2] - m[2], pm[3] - m[3]));
        if (__any(dmx >= -25.f)) {   // tile contributes for some q in the wave
            int kt0 = k0 + t * KBLK;
            #pragma unroll
            for (int g = 0; g < 4; ++g) {
                float v = pm[g];
                v = fmaxf(v, __shfl_xor(v, 16));
                v = fmaxf(v, __shfl_xor(v, 32));          // per-q tile max (uniform over lg)
                float mn = fmaxf(m[g], v);
                float al = exp2f(m[g] - mn);
                m[g] = mn;
                l[g] *= al;
                O[g][0] *= al; O[g][1] *= al; O[g][2] *= al;
            }
            float4 rv[2][3];
            #pragma unroll
            for (int s = 0; s < 2; ++s)
                #pragma unroll
                for (int c = 0; c < 3; ++c)
                    rv[s][c] = *(const float4*)(rgb + (size_t)(b * 3 + c) * kHW + kt0 + s * 16 + lg * 4);
            #pragma unroll
            for (int g = 0; g < 4; ++g) {
                #pragma unroll
                for (int s = 0; s < 2; ++s) {
                    float p0 = exp2f(acc[g][s][0] - m[g]);
                    float p1 = exp2f(acc[g][s][1] - m[g]);
                    float p2 = exp2f(acc[g][s][2] - m[g]);
                    float p3 = exp2f(acc[g][s][3] - m[g]);
                    l[g] += p0 + p1 + p2 + p3;
                    #pragma unroll
                    for (int c = 0; c < 3; ++c)
                        O[g][c] += p0 * rv[s][c].x + p1 * rv[s][c].y
                                 + p2 * rv[s][c].z + p3 * rv[s][c].w;
                }
            }
        }
        __syncthreads();   // prefetch landed; all waves done with buf
        buf ^= 1;
    }

    // final cross-kgroup (lg) reduction of per-lane partials
    #pragma unroll
    for (int g = 0; g < 4; ++g) {
        l[g] += __shfl_xor(l[g], 16); l[g] += __shfl_xor(l[g], 32);
        #pragma unroll
        for (int c = 0; c < 3; ++c) {
            O[g][c] += __shfl_xor(O[g][c], 16);
            O[g][c] += __shfl_xor(O[g][c], 32);
        }
    }
    if (lg == 0) {
        #pragma unroll
        for (int g = 0; g < 4; ++g) {
            int q = qwave + g * 16 + lr;
            float* p = part + ((size_t)(b * kHW + q) * KSPLIT + ks) * 5;
            p[0] = m[g]; p[1] = l[g]; p[2] = O[g][0]; p[3] = O[g][1]; p[4] = O[g][2];
        }
    }
}

// ---------------- Phase 3: merge the KSPLIT partials ----------------
__global__ __launch_bounds__(256)
void nlwa_merge(const float* __restrict__ part, float* __restrict__ out) {
    int idx = blockIdx.x * 256 + threadIdx.x;
    if (idx >= kB * kHW) return;
    int b = idx >> 12, q = idx & 4095;
    const float* p = part + (size_t)idx * KSPLIT * 5;
    float M = -INFINITY;
    #pragma unroll
    for (int s = 0; s < KSPLIT; ++s) M = fmaxf(M, p[s * 5]);
    float L = 0.f, o0 = 0.f, o1 = 0.f, o2 = 0.f;
    #pragma unroll
    for (int s = 0; s < KSPLIT; ++s) {
        float a = exp2f(p[s * 5] - M);
        L  += p[s * 5 + 1] * a;
        o0 += p[s * 5 + 2] * a;
        o1 += p[s * 5 + 3] * a;
        o2 += p[s * 5 + 4] * a;
    }
    float inv = 1.f / L;
    out[(b * 3 + 0) * kHW + q] = o0 * inv;
    out[(b * 3 + 1) * kHW + q] = o1 * inv;
    out[(b * 3 + 2) * kHW + q] = o2 * inv;
}

// ---------------- Fallback (ws too small): slow fp32, correct ----------------
__global__ __launch_bounds__(64)
void nlwa_naive(const float* __restrict__ feat, const float* __restrict__ rgb,
                float* __restrict__ out) {
    int p = blockIdx.x, b = blockIdx.y;
    int pi = p >> 6, pj = p & 63;
    int t = threadIdx.x;
    __shared__ float pdesc[kD];
    __shared__ float rows[kC][3][kW];
    __shared__ float red[64][5];

    for (int d = t; d < kD; d += 64) {
        int c = d / 9, dl = d % 9;
        int y = pi + dl / 3 - 1, x = pj + dl % 3 - 1;
        pdesc[d] = ((unsigned)y < 64u && (unsigned)x < 64u)
                 ? feat[((b * kC + c) * kH + y) * kW + x] : 0.f;
    }
    float m = -INFINITY, l = 0.f, O0 = 0.f, O1 = 0.f, O2 = 0.f;
    for (int qi = 0; qi < kH; ++qi) {
        __syncthreads();
        for (int f = t; f < kC * 3 * kW; f += 64) {
            int x = f & 63, yy = (f >> 6) % 3, c = f / (3 * kW);
            int y = qi + yy - 1;
            rows[c][yy][x] = ((unsigned)y < 64u) ? feat[((b * kC + c) * kH + y) * kW + x] : 0.f;
        }
        __syncthreads();
        float s = 0.f;
        for (int c = 0; c < kC; ++c)
            for (int dl = 0; dl < 9; ++dl) {
                int x = t + dl % 3 - 1;
                float fv = ((unsigned)x < 64u) ? rows[c][dl / 3][x] : 0.f;
                s += pdesc[c * 9 + dl] * fv;
            }
        s *= 14.4269504089f;
        int q = qi * 64 + t;
        float mn = fmaxf(m, s);
        float al = exp2f(m - mn);
        float pv = exp2f(s - mn);
        l = l * al + pv;
        O0 = O0 * al + pv * rgb[(b * 3 + 0) * kHW + q];
        O1 = O1 * al + pv * rgb[(b * 3 + 1) * kHW + q];
        O2 = O2 * al + pv * rgb[(b * 3 + 2) * kHW + q];
        m = mn;
    }
    red[t][0] = m; red[t][1] = l; red[t][2] = O0; red[t][3] = O1; red[t][4] = O2;
    __syncthreads();
    if (t == 0) {
        float M = -INFINITY;
        for (int i = 0; i < 64; ++i) M = fmaxf(M, red[i][0]);
        float L = 0, A = 0, Bv = 0, Cv = 0;
        for (int i = 0; i < 64; ++i) {
            float a = exp2f(red[i][0] - M);
            L += red[i][1] * a; A += red[i][2] * a; Bv += red[i][3] * a; Cv += red[i][4] * a;
        }
        out[(b * 3 + 0) * kHW + p] = A / L;
        out[(b * 3 + 1) * kHW + p] = Bv / L;
        out[(b * 3 + 2) * kHW + p] = Cv / L;
    }
}

extern "C" void kernel_launch(void* const* d_in, const int* in_sizes, int n_in,
                              void* d_out, int out_size, void* d_ws, size_t ws_size,
                              hipStream_t stream) {
    const float* x_rgb   = (const float*)d_in[0];   // [4,3,64,64]
    const float* feature = (const float*)d_in[1];   // [4,64,64,64]
    float* out = (float*)d_out;                     // [4,3,64,64]

    size_t needK = (size_t)kB * kHW * ROWB8;               // 10.49 MB fp8 K
    size_t needP = (size_t)kB * kHW * KSPLIT * 5 * 4;      // 2.62 MB partials
    size_t needS = (size_t)kB * kHW * 4;                   // 64 KB selfsq
    if (ws_size >= needK + needP + needS) {
        unsigned char* Kd = (unsigned char*)d_ws;
        float* partb = (float*)((char*)d_ws + needK);
        float* sqb   = (float*)((char*)d_ws + needK + needP);
        int total = kB * kHW * kD;
        nlwa_selfsq<<<(kB * kHW + 255) / 256, 256, 0, stream>>>(feature, sqb);
        nlwa_unfold<<<(total + 255) / 256, 256, 0, stream>>>(feature, Kd);
        nlwa_attn<<<kB * (kHW / QWG) * KSPLIT, 128, 0, stream>>>(Kd, x_rgb, sqb, partb);
        nlwa_merge<<<(kB * kHW + 255) / 256, 256, 0, stream>>>(partb, out);
    } else {
        nlwa_naive<<<dim3(kHW, kB), 64, 0, stream>>>(feature, x_rgb, out);
    }
}

// Round 7
// 89.579 us; speedup vs baseline: 1.4520x; 1.4520x over previous
//
#include <hip/hip_runtime.h>
#include <hip/hip_bf16.h>

typedef __attribute__((ext_vector_type(4))) float f32x4;
typedef __attribute__((ext_vector_type(2))) long long l64x2;

constexpr int kB = 4, kC = 64, kH = 64, kW = 64;
constexpr int kHW = kH * kW;      // 4096
constexpr int kD  = kC * 9;       // 576
constexpr int KSPLIT = 8;
constexpr int KBLK = 16;          // k rows per tile (1 MFMA row-block)
constexpr int QWAVE = 32;         // q rows per wave (2 groups of 16)
constexpr int QWG = 128;          // 4 waves * 32 q
constexpr int NTILE = kHW / KSPLIT / KBLK;   // 32
constexpr int ROWB8 = 640;        // padded fp8 row bytes (40 chunks of 16B; 36 data + 4 holes)
constexpr int TILEB = KBLK * ROWB8;          // 10240 B per K-tile
constexpr int TCHUNK = TILEB / 16;           // 640 16B-chunks per tile

// Features pre-scaled by sqrt(10*log2e): S = corr in exp2-logit space.
#define FSCALE 3.79828370f
#define FS2    14.4269504089f     // FSCALE^2 = 10*log2(e)
#define SEED_SLACK 64.0f          // fp32-seed vs fp8-diag tolerance

// ---------------- Phase 0: per-pixel sum of squared channels (for self-logit seed) ----------------
__global__ __launch_bounds__(256)
void nlwa_selfsq(const float* __restrict__ feat, float* __restrict__ sq) {
    int idx = blockIdx.x * 256 + threadIdx.x;   // b*4096 + p
    if (idx >= kB * kHW) return;
    int b = idx >> 12, p = idx & 4095;
    const float* f = feat + (size_t)b * kC * kHW + p;
    float s = 0.f;
    #pragma unroll 8
    for (int c = 0; c < kC; ++c) { float v = f[c * kHW]; s = fmaf(v, v, s); }
    sq[idx] = s;
}

// ---------------- Phase 1: unfold + fp8(e4m3) + pre-scale + XOR pre-swizzle ----------------
// d decomposed: window w=d>>5, kgroup kg=(d>>3)&3, elem e=d&7.
// logical 16B-chunk c = (w>>1)*4+kg (0..35); physical chunk = c ^ (v&7) in 40-chunk padded row.
__global__ __launch_bounds__(256)
void nlwa_unfold(const float* __restrict__ feat, unsigned char* __restrict__ Kd) {
    int idx = blockIdx.x * 256 + threadIdx.x;
    if (idx >= kB * kHW * kD) return;
    int d = idx % kD;
    int v = (idx / kD) % kHW;
    int b = idx / (kD * kHW);
    int c = d / 9, dl = d % 9;
    int y = (v >> 6) + dl / 3 - 1;
    int x = (v & 63) + dl % 3 - 1;
    float val = 0.f;
    if ((unsigned)y < 64u && (unsigned)x < 64u)
        val = feat[((b * kC + c) * kH + y) * kW + x] * FSCALE;
    // e4m3 encode via exponent-shift trick (|val| < 448, no NaN/Inf)
    unsigned int fb = __builtin_bit_cast(unsigned int, val * 0x1p-120f);
    unsigned int mag = ((fb & 0x7fffffffu) + 0x80000u) >> 20;
    if (mag > 0x7eu) mag = 0x7eu;
    unsigned char u8 = (unsigned char)(((fb >> 31) << 7) | mag);
    int w = d >> 5, kg = (d >> 3) & 3, e = d & 7;
    int cp = ((w >> 1) * 4 + kg) ^ (v & 7);
    Kd[(size_t)(b * kHW + v) * ROWB8 + cp * 16 + (w & 1) * 8 + e] = u8;
}

// ---------------- Phase 2: flash attention, swapped mfma(K,Q) in fp8, 32 q/wave ----------------
// Resource budget: <=128 VGPR/wave (qb=72 + ~55 misc), 20KB LDS/block -> 16 waves/CU.
__global__ __launch_bounds__(256, 4)
void nlwa_attn(const unsigned char* __restrict__ Kd,
               const float* __restrict__ rgb,
               const float* __restrict__ sq,
               float* __restrict__ part) {
    __shared__ alignas(16) unsigned char Ks[2][KBLK][ROWB8];   // 20,480 B

    // XCD-chunked swizzle: 1024 wgs -> 128 consecutive per XCD (4 (b,ks) panels ~1.3MB + Q in its L2)
    int orig = blockIdx.x;
    int wg = (orig & 7) * 128 + (orig >> 3);
    int qblk = wg & 31;
    int pr = wg >> 5;
    int ks = pr & 7;
    int b  = pr >> 3;

    int tid = threadIdx.x, lane = tid & 63, wid = tid >> 6;
    int lr = lane & 15, lg = lane >> 4;       // lg = k-chunk group
    int x7 = lr & 7;
    int qwave = qblk * QWG + wid * QWAVE;
    int k0 = ks * (kHW / KSPLIT);             // ks*512

    // ---- Q fragments (B-operand): 2 groups x 9 chunk-pairs, int4 = 2 windows each ----
    int4 qb[2][9];
    #pragma unroll
    for (int g = 0; g < 2; ++g) {
        const unsigned char* qbase = Kd + (size_t)(b * kHW + qwave + g * 16 + lr) * ROWB8;
        #pragma unroll
        for (int p = 0; p < 9; ++p)
            qb[g][p] = *(const int4*)(qbase + (((p * 4 + lg) ^ x7) << 4));
    }

    // ---- Seed m with fp32 self-logit (3x3 box-sum of per-pixel sum-sq) minus slack ----
    float m[2], l[2] = {0.f, 0.f};
    float O[2][3] = {{0,0,0},{0,0,0}};
    const float* sqb = sq + b * kHW;
    #pragma unroll
    for (int g = 0; g < 2; ++g) {
        int q = qwave + g * 16 + lr, y = q >> 6, x = q & 63;
        float s = 0.f;
        #pragma unroll
        for (int dy = -1; dy <= 1; ++dy)
            #pragma unroll
            for (int dx = -1; dx <= 1; ++dx) {
                int yy = y + dy, xx = x + dx;
                if ((unsigned)yy < 64u && (unsigned)xx < 64u) s += sqb[yy * 64 + xx];
            }
        m[g] = s * FS2 - SEED_SLACK;
    }

    const unsigned char* ksrc = Kd + (size_t)(b * kHW + k0) * ROWB8;
    unsigned char* lds0 = &Ks[0][0][0];

    auto stage = [&](int t, int bufi) {   // flat 10,240-B copy: 640 chunks, 2.5 iters x 256 thr
        const unsigned char* src = ksrc + (size_t)t * TILEB;
        unsigned char* dstb = lds0 + bufi * TILEB;
        #pragma unroll
        for (int it = 0; it < 3; ++it) {
            int base = it * 256 + wid * 64;   // wave-uniform chunk base
            if (base < TCHUNK) {              // wave-uniform guard (it=2: only wid 0,1)
                __builtin_amdgcn_global_load_lds(
                    (const __attribute__((address_space(1))) void*)(src + (size_t)(base + lane) * 16),
                    (__attribute__((address_space(3))) void*)(dstb + (size_t)base * 16),
                    16, 0, 0);
            }
        }
    };

    stage(0, 0);
    __syncthreads();   // tile 0 resident

    // Per-lane LDS read offsets: physical chunk (p*4+lg)^x7 = (p^h)*4 + (lg^lo2)
    int lo2 = x7 & 3, h = x7 >> 2;
    int r0 = lr * ROWB8 + ((lg ^ lo2) << 4);
    int e0 = r0 + h * 64, o0 = r0 - h * 64;   // even-p / odd-p bases

    int buf = 0;
    for (int t = 0; t < NTILE; ++t) {
        if (t + 1 < NTILE) stage(t + 1, buf ^ 1);   // prefetch next into other buffer

        const unsigned char* kb = lds0 + buf * TILEB;
        f32x4 acc[2];
        acc[0] = (f32x4){0.f, 0.f, 0.f, 0.f};
        acc[1] = (f32x4){0.f, 0.f, 0.f, 0.f};

        #pragma unroll
        for (int p = 0; p < 9; ++p) {
            int4 ka = *(const int4*)(kb + ((p & 1) ? o0 : e0) + p * 64);
            l64x2 ka64 = __builtin_bit_cast(l64x2, ka);
            #pragma unroll
            for (int w01 = 0; w01 < 2; ++w01) {
                long long a0 = ka64[w01];
                #pragma unroll
                for (int g = 0; g < 2; ++g) {
                    long long bq = __builtin_bit_cast(l64x2, qb[g][p])[w01];
                    acc[g] = __builtin_amdgcn_mfma_f32_16x16x32_fp8_fp8(a0, bq, acc[g], 0, 0, 0);
                }
            }
        }
        // acc[g][r] = S[k = k0 + t*16 + lg*4 + r][q = qwave + g*16 + lr]

        float pm[2];
        #pragma unroll
        for (int g = 0; g < 2; ++g)
            pm[g] = fmaxf(fmaxf(acc[g][0], acc[g][1]), fmaxf(acc[g][2], acc[g][3]));

        float dmx = fmaxf(pm[0] - m[0], pm[1] - m[1]);
        if (__any(dmx >= -25.f)) {   // tile contributes for some q in the wave
            int kt0 = k0 + t * KBLK;
            #pragma unroll
            for (int g = 0; g < 2; ++g) {
                float v = pm[g];
                v = fmaxf(v, __shfl_xor(v, 16));
                v = fmaxf(v, __shfl_xor(v, 32));          // per-q tile max (uniform over lg)
                float mn = fmaxf(m[g], v);
                float al = exp2f(m[g] - mn);
                m[g] = mn;
                l[g] *= al;
                O[g][0] *= al; O[g][1] *= al; O[g][2] *= al;
            }
            float4 rv[3];
            #pragma unroll
            for (int c = 0; c < 3; ++c)
                rv[c] = *(const float4*)(rgb + (size_t)(b * 3 + c) * kHW + kt0 + lg * 4);
            #pragma unroll
            for (int g = 0; g < 2; ++g) {
                float p0 = exp2f(acc[g][0] - m[g]);
                float p1 = exp2f(acc[g][1] - m[g]);
                float p2 = exp2f(acc[g][2] - m[g]);
                float p3 = exp2f(acc[g][3] - m[g]);
                l[g] += p0 + p1 + p2 + p3;
                #pragma unroll
                for (int c = 0; c < 3; ++c)
                    O[g][c] += p0 * rv[c].x + p1 * rv[c].y + p2 * rv[c].z + p3 * rv[c].w;
            }
        }
        __syncthreads();   // prefetch landed; all waves done with buf
        buf ^= 1;
    }

    // final cross-kgroup (lg) reduction of per-lane partials
    #pragma unroll
    for (int g = 0; g < 2; ++g) {
        l[g] += __shfl_xor(l[g], 16); l[g] += __shfl_xor(l[g], 32);
        #pragma unroll
        for (int c = 0; c < 3; ++c) {
            O[g][c] += __shfl_xor(O[g][c], 16);
            O[g][c] += __shfl_xor(O[g][c], 32);
        }
    }
    if (lg == 0) {
        #pragma unroll
        for (int g = 0; g < 2; ++g) {
            int q = qwave + g * 16 + lr;
            float* p = part + ((size_t)(b * kHW + q) * KSPLIT + ks) * 5;
            p[0] = m[g]; p[1] = l[g]; p[2] = O[g][0]; p[3] = O[g][1]; p[4] = O[g][2];
        }
    }
}

// ---------------- Phase 3: merge the KSPLIT partials ----------------
__global__ __launch_bounds__(256)
void nlwa_merge(const float* __restrict__ part, float* __restrict__ out) {
    int idx = blockIdx.x * 256 + threadIdx.x;
    if (idx >= kB * kHW) return;
    int b = idx >> 12, q = idx & 4095;
    const float* p = part + (size_t)idx * KSPLIT * 5;
    float M = -INFINITY;
    #pragma unroll
    for (int s = 0; s < KSPLIT; ++s) M = fmaxf(M, p[s * 5]);
    float L = 0.f, o0 = 0.f, o1 = 0.f, o2 = 0.f;
    #pragma unroll
    for (int s = 0; s < KSPLIT; ++s) {
        float a = exp2f(p[s * 5] - M);
        L  += p[s * 5 + 1] * a;
        o0 += p[s * 5 + 2] * a;
        o1 += p[s * 5 + 3] * a;
        o2 += p[s * 5 + 4] * a;
    }
    float inv = 1.f / L;
    out[(b * 3 + 0) * kHW + q] = o0 * inv;
    out[(b * 3 + 1) * kHW + q] = o1 * inv;
    out[(b * 3 + 2) * kHW + q] = o2 * inv;
}

// ---------------- Fallback (ws too small): slow fp32, correct ----------------
__global__ __launch_bounds__(64)
void nlwa_naive(const float* __restrict__ feat, const float* __restrict__ rgb,
                float* __restrict__ out) {
    int p = blockIdx.x, b = blockIdx.y;
    int pi = p >> 6, pj = p & 63;
    int t = threadIdx.x;
    __shared__ float pdesc[kD];
    __shared__ float rows[kC][3][kW];
    __shared__ float red[64][5];

    for (int d = t; d < kD; d += 64) {
        int c = d / 9, dl = d % 9;
        int y = pi + dl / 3 - 1, x = pj + dl % 3 - 1;
        pdesc[d] = ((unsigned)y < 64u && (unsigned)x < 64u)
                 ? feat[((b * kC + c) * kH + y) * kW + x] : 0.f;
    }
    float m = -INFINITY, l = 0.f, O0 = 0.f, O1 = 0.f, O2 = 0.f;
    for (int qi = 0; qi < kH; ++qi) {
        __syncthreads();
        for (int f = t; f < kC * 3 * kW; f += 64) {
            int x = f & 63, yy = (f >> 6) % 3, c = f / (3 * kW);
            int y = qi + yy - 1;
            rows[c][yy][x] = ((unsigned)y < 64u) ? feat[((b * kC + c) * kH + y) * kW + x] : 0.f;
        }
        __syncthreads();
        float s = 0.f;
        for (int c = 0; c < kC; ++c)
            for (int dl = 0; dl < 9; ++dl) {
                int x = t + dl % 3 - 1;
                float fv = ((unsigned)x < 64u) ? rows[c][dl / 3][x] : 0.f;
                s += pdesc[c * 9 + dl] * fv;
            }
        s *= 14.4269504089f;
        int q = qi * 64 + t;
        float mn = fmaxf(m, s);
        float al = exp2f(m - mn);
        float pv = exp2f(s - mn);
        l = l * al + pv;
        O0 = O0 * al + pv * rgb[(b * 3 + 0) * kHW + q];
        O1 = O1 * al + pv * rgb[(b * 3 + 1) * kHW + q];
        O2 = O2 * al + pv * rgb[(b * 3 + 2) * kHW + q];
        m = mn;
    }
    red[t][0] = m; red[t][1] = l; red[t][2] = O0; red[t][3] = O1; red[t][4] = O2;
    __syncthreads();
    if (t == 0) {
        float M = -INFINITY;
        for (int i = 0; i < 64; ++i) M = fmaxf(M, red[i][0]);
        float L = 0, A = 0, Bv = 0, Cv = 0;
        for (int i = 0; i < 64; ++i) {
            float a = exp2f(red[i][0] - M);
            L += red[i][1] * a; A += red[i][2] * a; Bv += red[i][3] * a; Cv += red[i][4] * a;
        }
        out[(b * 3 + 0) * kHW + p] = A / L;
        out[(b * 3 + 1) * kHW + p] = Bv / L;
        out[(b * 3 + 2) * kHW + p] = Cv / L;
    }
}

extern "C" void kernel_launch(void* const* d_in, const int* in_sizes, int n_in,
                              void* d_out, int out_size, void* d_ws, size_t ws_size,
                              hipStream_t stream) {
    const float* x_rgb   = (const float*)d_in[0];   // [4,3,64,64]
    const float* feature = (const float*)d_in[1];   // [4,64,64,64]
    float* out = (float*)d_out;                     // [4,3,64,64]

    size_t needK = (size_t)kB * kHW * ROWB8;               // 10.49 MB fp8 K
    size_t needP = (size_t)kB * kHW * KSPLIT * 5 * 4;      // 2.62 MB partials
    size_t needS = (size_t)kB * kHW * 4;                   // 64 KB selfsq
    if (ws_size >= needK + needP + needS) {
        unsigned char* Kd = (unsigned char*)d_ws;
        float* partb = (float*)((char*)d_ws + needK);
        float* sqb   = (float*)((char*)d_ws + needK + needP);
        int total = kB * kHW * kD;
        nlwa_selfsq<<<(kB * kHW + 255) / 256, 256, 0, stream>>>(feature, sqb);
        nlwa_unfold<<<(total + 255) / 256, 256, 0, stream>>>(feature, Kd);
        nlwa_attn<<<kB * (kHW / QWG) * KSPLIT, 256, 0, stream>>>(Kd, x_rgb, sqb, partb);
        nlwa_merge<<<(kB * kHW + 255) / 256, 256, 0, stream>>>(partb, out);
    } else {
        nlwa_naive<<<dim3(kHW, kB), 64, 0, stream>>>(feature, x_rgb, out);
    }
}